// Round 21
// baseline (136.186 us; speedup 1.0000x reference)
//
#include <hip/hip_runtime.h>
#include <hip/hip_bf16.h>
#include <math.h>

#define DEV_INLINE __device__ __forceinline__

typedef __attribute__((ext_vector_type(4))) float f32x4;
typedef __attribute__((ext_vector_type(16))) float f32x16;
typedef __attribute__((ext_vector_type(8))) short short8;
typedef __attribute__((ext_vector_type(4))) unsigned short u16x4;

// ---------- bf16 helpers ----------
DEV_INLINE unsigned short f2bf(float f) {
    unsigned int u = __builtin_bit_cast(unsigned int, f);
    u += 0x7FFFu + ((u >> 16) & 1u);   // round-to-nearest-even
    return (unsigned short)(u >> 16);
}
DEV_INLINE float bf2f(unsigned short h) {
    unsigned int u = ((unsigned int)h) << 16;
    return __builtin_bit_cast(float, u);
}
DEV_INLINE unsigned cvt_pk_bf16(float lo, float hi) {
    unsigned r;
    asm("v_cvt_pk_bf16_f32 %0, %1, %2" : "=v"(r) : "v"(lo), "v"(hi));
    return r;
}

// ---------- async global->LDS (16B per lane) ----------
DEV_INLINE void gload16(const void* g, void* l) {
    __builtin_amdgcn_global_load_lds(
        (const __attribute__((address_space(1))) unsigned int*)g,
        (__attribute__((address_space(3))) unsigned int*)l, 16, 0, 0);
}

// ---------- constants ----------
#define BB 2
#define TT 2048
#define DD 1024
#define HH 16
#define HDIM 64
#define BT (BB*TT)        // 4096
#define N3 (3*DD)         // 3072
#define NROWS (BB*HH*TT)  // 65536 attention rows
#define K1ATT 0.18033688011112042f   // (1/8) * log2(e), folded into Q

#define SPLIT 2
#define KVLEN (TT/SPLIT)   // 1024 keys per split
#define NTILE (KVLEN/32)   // 32 tiles per split

// ============================================================
// Fused prep kernel (block-range dispatch)
// ============================================================
DEV_INLINE void do_transpose(const float* __restrict__ in, unsigned short* __restrict__ out,
                             int K, int N, int bx, float (*tile)[66], int tid) {
    int nb = N >> 6;
    int n0 = (bx % nb) * 64, k0 = (bx / nb) * 64;
    int tx = tid & 63, ty = tid >> 6;
#pragma unroll
    for (int r = ty; r < 64; r += 4)
        tile[r][tx] = in[(size_t)(k0 + r) * N + n0 + tx];
    __syncthreads();
#pragma unroll
    for (int r = ty; r < 64; r += 4)
        out[(size_t)(n0 + r) * K + k0 + tx] = f2bf(tile[tx][r]);
}

__global__ __launch_bounds__(256)
void k_prep(const float* __restrict__ x, const float* __restrict__ W_qkv,
            const float* __restrict__ W_out, const unsigned char* __restrict__ mask,
            unsigned short* __restrict__ xb, float2* __restrict__ cs,
            unsigned short* __restrict__ wqkvt, unsigned short* __restrict__ woutt,
            unsigned* __restrict__ mbits) {
    __shared__ float tile[64][66];
    const int bid = blockIdx.x, tid = threadIdx.x;
    if (bid < 4096) {
        int i = bid * 256 + tid;
        f32x4 v = ((const f32x4*)x)[i];
        u16x4 o;
        o[0] = f2bf(v[0]); o[1] = f2bf(v[1]); o[2] = f2bf(v[2]); o[3] = f2bf(v[3]);
        ((u16x4*)xb)[i] = o;
    } else if (bid < 4352) {
        int i = (bid - 4096) * 256 + tid;
        int t = i >> 5, f = i & 31;
        float inv = powf(10000.0f, -(float)f / 32.0f);
        float ang = (float)t * inv;
        cs[i] = make_float2(cosf(ang), sinf(ang));
    } else if (bid < 5120) {
        do_transpose(W_qkv, wqkvt, DD, N3, bid - 4352, tile, tid);
    } else if (bid < 5376) {
        do_transpose(W_out, woutt, DD, DD, bid - 5120, tile, tid);
    } else {
        if (tid < BB * 64) {
            int b = tid >> 6, w = tid & 63;
            unsigned v = 0;
#pragma unroll
            for (int j = 0; j < 32; ++j)
                v |= (mask[b * TT + w * 32 + j] ? 1u : 0u) << j;
            mbits[tid] = v;
        }
    }
}

// ============================================================
// Shared BK=64 GEMM core (R17-proven): 128x128 tile, 16 K-steps.
// XOR-swizzled LDS (both-sides rule).
// ============================================================
#define GEMM64_BODY(A_, Bt_, m0_, n0_, K_)                                          \
    f32x4 acc[4][4] = {};                                                           \
    for (int k0 = 0; k0 < (K_); k0 += 64) {                                         \
        __syncthreads();                                                            \
        _Pragma("unroll")                                                           \
        for (int i = 0; i < 4; ++i) {                                               \
            int c    = i * 256 + tid;                                               \
            int row  = c >> 3;                                                      \
            int dstc = c & 7;                                                       \
            int srcc = dstc ^ (row & 7);                                            \
            unsigned short* ldsA = As + (size_t)(i * 256 + wave * 64) * 8;          \
            unsigned short* ldsB = Bs + (size_t)(i * 256 + wave * 64) * 8;          \
            gload16(A_  + (size_t)((m0_) + row) * (K_) + k0 + srcc * 8, ldsA);      \
            gload16(Bt_ + (size_t)((n0_) + row) * (K_) + k0 + srcc * 8, ldsB);      \
        }                                                                           \
        __syncthreads();                                                            \
        _Pragma("unroll")                                                           \
        for (int kk = 0; kk < 2; ++kk) {                                            \
            short8 af[4], bfr[4];                                                   \
            _Pragma("unroll")                                                       \
            for (int m = 0; m < 4; ++m) {                                           \
                int R  = wr * 64 + m * 16 + lrow;                                   \
                int ch = (kk * 4 + (lane >> 4)) ^ (R & 7);                          \
                af[m] = *(const short8*)(As + R * 64 + ch * 8);                     \
            }                                                                       \
            _Pragma("unroll")                                                       \
            for (int n = 0; n < 4; ++n) {                                           \
                int R  = wc * 64 + n * 16 + lrow;                                   \
                int ch = (kk * 4 + (lane >> 4)) ^ (R & 7);                          \
                bfr[n] = *(const short8*)(Bs + R * 64 + ch * 8);                    \
            }                                                                       \
            _Pragma("unroll")                                                       \
            for (int m = 0; m < 4; ++m)                                             \
                _Pragma("unroll")                                                   \
                for (int n = 0; n < 4; ++n)                                         \
                    acc[m][n] = __builtin_amdgcn_mfma_f32_16x16x32_bf16(            \
                        af[m], bfr[n], acc[m][n], 0, 0, 0);                         \
        }                                                                           \
    }

// ============================================================
// QKV GEMM + fused bias + RoPE + scatter. BK=64 core.
// V written transposed directly (R19-proven).
// ============================================================
__global__ __launch_bounds__(256)
void k_gemm_qkv(const unsigned short* __restrict__ A,
                const unsigned short* __restrict__ Bt,
                const float* __restrict__ bias,
                const float2* __restrict__ cs,
                unsigned short* __restrict__ Qb,
                unsigned short* __restrict__ Kb,
                unsigned short* __restrict__ Vt) {
    __shared__ unsigned short As[128 * 64];
    __shared__ unsigned short Bs[128 * 64];
    const int tid  = threadIdx.x;
    const int lane = tid & 63;
    const int wave = tid >> 6;
    const int wr = wave >> 1, wc = wave & 1;
    const int bid = blockIdx.x;
    const int xcd = bid & 7, loc = bid >> 3;                 // loc 0..95
    const int m0 = ((xcd >> 1) * 8 + (loc & 7)) * 128;       // 32 m-tiles
    const int n0 = ((xcd & 1) * 12 + (loc >> 3)) * 128;      // 24 n-tiles
    const int lrow = lane & 15;

    GEMM64_BODY(A, Bt, m0, n0, DD)

    const int part = n0 >> 10;                       // 0=Q 1=K 2=V
    const int n0c  = n0 + wc * 64;
    const int h    = ((n0 & 1023) + wc * 64) >> 6;

    if (part < 2) {
        unsigned short* Dst = part == 0 ? Qb : Kb;
        const float qs = part == 0 ? K1ATT : 1.0f;
#pragma unroll
        for (int m = 0; m < 4; ++m)
#pragma unroll
            for (int r = 0; r < 4; ++r) {
                int gm = m0 + wr * 64 + m * 16 + (lane >> 4) * 4 + r;
                int b = gm >> 11, t = gm & (TT - 1);
                size_t rowoff = ((size_t)(b * HH + h) * TT + t) * 64;
#pragma unroll
                for (int n = 0; n < 2; ++n) {
                    int dr = n * 16 + lrow;
                    float2 c2 = cs[t * 32 + dr];
                    float lo = acc[m][n][r]     + bias[n0c + dr];
                    float hi = acc[m][n + 2][r] + bias[n0c + 32 + dr];
                    Dst[rowoff + dr]      = f2bf((lo * c2.x - hi * c2.y) * qs);
                    Dst[rowoff + 32 + dr] = f2bf((hi * c2.x + lo * c2.y) * qs);
                }
            }
    } else {
        // V: direct transposed write
#pragma unroll
        for (int m = 0; m < 4; ++m) {
            int gm0 = m0 + wr * 64 + m * 16 + (lane >> 4) * 4;  // 4 consecutive t
            int b = gm0 >> 11, t = gm0 & (TT - 1);
#pragma unroll
            for (int n = 0; n < 4; ++n) {
                int d = n * 16 + lrow;
                float bv = bias[n0c + d];
                u16x4 v;
#pragma unroll
                for (int r = 0; r < 4; ++r) v[r] = f2bf(acc[m][n][r] + bv);
                *(u16x4*)(Vt + ((size_t)(b * HH + h) * 64 + d) * TT + t) = v;
            }
        }
    }
}

// ============================================================
// Output GEMM with FUSED split-combine (R20-proven).
// Tile 64x128, grid 512 (2 blocks/CU); 4 waves as 1x4.
// ============================================================
__global__ __launch_bounds__(256)
void k_gemm_out(const unsigned short* __restrict__ Opart,
                const float* __restrict__ lbuf,
                const unsigned short* __restrict__ Bt,
                const float* __restrict__ bias,
                float* __restrict__ C) {
    __shared__ unsigned short As[64 * 64];     // 8 KB
    __shared__ unsigned short Bs[128 * 64];    // 16 KB
    const int tid  = threadIdx.x;
    const int lane = tid & 63;
    const int wave = tid >> 6;
    const int bid = blockIdx.x;
    const int xcd = bid & 7, loc = bid >> 3;                 // loc 0..63
    const int m0 = ((xcd >> 1) * 16 + (loc & 15)) * 64;      // 64 m-tiles
    const int n0 = ((xcd & 1) * 4 + (loc >> 4)) * 128;       // 8 n-tiles
    const int lrow = lane & 15;
    const int N = DD, K = DD;

    f32x4 acc[4][2] = {};

    for (int k0 = 0; k0 < K; k0 += 64) {
        const int h = k0 >> 6;                 // head for this K-step
        __syncthreads();
        // ---- A: reg-staged combine (2 slots/thread) ----
#pragma unroll
        for (int i = 0; i < 2; ++i) {
            int c     = i * 256 + tid;
            int row   = c >> 3;                // 0..63 (tile row)
            int chunk = c & 7;                 // d-chunk
            int gm = m0 + row;
            int b  = gm >> 11, t = gm & (TT - 1);
            size_t g = (size_t)(b * HH + h) * TT + t;
            short8 va = *(const short8*)(Opart + g * 64 + chunk * 8);
            short8 vb = *(const short8*)(Opart + ((size_t)NROWS + g) * 64 + chunk * 8);
            float inv = 1.0f / (lbuf[g] + lbuf[NROWS + g]);
            short8 o;
#pragma unroll
            for (int e = 0; e < 8; ++e)
                o[e] = (short)f2bf((bf2f((unsigned short)va[e]) + bf2f((unsigned short)vb[e])) * inv);
            *(short8*)(As + row * 64 + (chunk ^ (row & 7)) * 8) = o;
        }
        // ---- B: gload16 (4 slots/thread), inverse-swizzled source ----
#pragma unroll
        for (int i = 0; i < 4; ++i) {
            int c    = i * 256 + tid;
            int row  = c >> 3;
            int dstc = c & 7;
            int srcc = dstc ^ (row & 7);
            gload16(Bt + (size_t)(n0 + row) * K + k0 + srcc * 8,
                    &Bs[(size_t)(i * 256 + wave * 64) * 8]);
        }
        __syncthreads();
        // ---- compute: wave covers m 0..63, n wave*32..+32 ----
#pragma unroll
        for (int kk = 0; kk < 2; ++kk) {
            short8 af[4], bfr[2];
#pragma unroll
            for (int m = 0; m < 4; ++m) {
                int R  = m * 16 + lrow;
                int ch = (kk * 4 + (lane >> 4)) ^ (R & 7);
                af[m] = *(const short8*)(As + R * 64 + ch * 8);
            }
#pragma unroll
            for (int n = 0; n < 2; ++n) {
                int R  = wave * 32 + n * 16 + lrow;
                int ch = (kk * 4 + (lane >> 4)) ^ (R & 7);
                bfr[n] = *(const short8*)(Bs + R * 64 + ch * 8);
            }
#pragma unroll
            for (int m = 0; m < 4; ++m)
#pragma unroll
                for (int n = 0; n < 2; ++n)
                    acc[m][n] = __builtin_amdgcn_mfma_f32_16x16x32_bf16(
                        af[m], bfr[n], acc[m][n], 0, 0, 0);
        }
    }

#pragma unroll
    for (int m = 0; m < 4; ++m) {
        int row = m0 + m * 16 + (lane >> 4) * 4;
#pragma unroll
        for (int n = 0; n < 2; ++n) {
            int col = n0 + wave * 32 + n * 16 + lrow;
            float bv = bias[col];
#pragma unroll
            for (int r = 0; r < 4; ++r)
                C[(size_t)(row + r) * N + col] = acc[m][n][r] + bv;
        }
    }
}

// ============================================================
// Flash attention: swapped-QK^T 32x32, KVBLK=32, LDS dbuf,
// fixed-max softmax, SPLIT=2, XCD swizzle, bf16 partials.
// NEW vs R20: (1) l computed by MFMA (P x ones-B accumulated in
// ol) -- deletes the per-tile VALU sum tree, moves work to the
// less-busy MFMA pipe; each lane then holds l for its own 16
// q-rows (no cross-lane epilogue reduce). (2) s_setprio removed
// (4-wave lockstep = m190's measured-negative regime).
// ============================================================
__global__ __launch_bounds__(256, 4)
void k_attn(const unsigned short* __restrict__ Q,
            const unsigned short* __restrict__ Kg,
            const unsigned short* __restrict__ Vt,
            const unsigned* __restrict__ mbits,
            unsigned short* __restrict__ Opart, float* __restrict__ lbuf) {
    __shared__ unsigned short lds[2][2][2048];   // [buf][K/V][32x64]
    const int tid = threadIdx.x, lane = tid & 63, wave = tid >> 6;
    const int bid = blockIdx.x;
    const int w   = (bid & 7) * 128 + (bid >> 3);
    const int qx  = w & 15;
    const int z   = (w >> 4) & 1;
    const int bh  = w >> 5;
    const int b   = bh >> 4;
    const int q0  = (qx * 4 + wave) * 32;
    const int lq  = lane & 31;
    const int hi  = lane >> 5;
    const int k0  = z * KVLEN;

    const unsigned short* Qp = Q  + ((size_t)bh * TT + q0) * 64;
    const unsigned short* Kp = Kg + (size_t)bh * TT * 64 + (size_t)k0 * 64;
    const unsigned short* Vp = Vt + (size_t)bh * 64 * TT + k0;

    unsigned mwv = mbits[b * 64 + z * 32 + lq];

    const int rr = wave * 8 + (lane >> 3);
    const int j  = (lane & 7) ^ (rr & 7);
    const size_t ksrc = (size_t)rr * 64 + j * 8;
    const int vd = rr + ((j >> 2) << 5);
    const size_t vsrc = (size_t)vd * TT + (j & 3) * 8;

    short8 qf[4];
#pragma unroll
    for (int c = 0; c < 4; ++c)
        qf[c] = *(const short8*)(Qp + lq * 64 + c * 16 + hi * 8);

    f32x16 o0 = {}, o1 = {}, ol = {};
    // constant all-ones bf16 B-operand (layout-independent)
    union { unsigned w[4]; short8 v; } ones;
    ones.w[0] = ones.w[1] = ones.w[2] = ones.w[3] = 0x3F803F80u;
    const int rx = lq & 7;

    auto stage = [&](int tt, int buf) {
        gload16(Kp + (size_t)tt * 32 * 64 + ksrc, &lds[buf][0][wave * 512]);
        gload16(Vp + tt * 32 + vsrc,              &lds[buf][1][wave * 512]);
    };

    auto tile_compute = [&](const unsigned short* Kl, const unsigned short* Vl, int t) {
        short8 kf0 = *(const short8*)(Kl + lq * 64 + ((0 + hi) ^ rx) * 8);
        short8 kf1 = *(const short8*)(Kl + lq * 64 + ((2 + hi) ^ rx) * 8);
        short8 kf2 = *(const short8*)(Kl + lq * 64 + ((4 + hi) ^ rx) * 8);
        short8 kf3 = *(const short8*)(Kl + lq * 64 + ((6 + hi) ^ rx) * 8);
        short8 vf00 = *(const short8*)(Vl + lq * 64 + ((0 + hi) ^ rx) * 8);
        short8 vf10 = *(const short8*)(Vl + lq * 64 + ((2 + hi) ^ rx) * 8);
        short8 vf01 = *(const short8*)(Vl + lq * 64 + ((4 + hi) ^ rx) * 8);
        short8 vf11 = *(const short8*)(Vl + lq * 64 + ((6 + hi) ^ rx) * 8);

        f32x16 s = {};
        s = __builtin_amdgcn_mfma_f32_32x32x16_bf16(kf0, qf[0], s, 0, 0, 0);
        s = __builtin_amdgcn_mfma_f32_32x32x16_bf16(kf1, qf[1], s, 0, 0, 0);
        s = __builtin_amdgcn_mfma_f32_32x32x16_bf16(kf2, qf[2], s, 0, 0, 0);
        s = __builtin_amdgcn_mfma_f32_32x32x16_bf16(kf3, qf[3], s, 0, 0, 0);

        unsigned mw = __builtin_amdgcn_readlane(mwv, t);
        float p[16];
        if (mw) {                                   // wave-uniform rare path
            unsigned bmh = mw >> (hi * 4);
#pragma unroll
            for (int r = 0; r < 16; ++r) {
                float v = s[r];
                if ((bmh >> ((r & 3) + 8 * (r >> 2))) & 1u) v = -INFINITY;
                p[r] = __builtin_amdgcn_exp2f(v);
            }
        } else {
#pragma unroll
            for (int r = 0; r < 16; ++r) p[r] = __builtin_amdgcn_exp2f(s[r]);
        }

        unsigned u[8];
#pragma unroll
        for (int i = 0; i < 8; ++i) u[i] = cvt_pk_bf16(p[2 * i], p[2 * i + 1]);

        unsigned s0 = hi ? u[0] : u[2];
        unsigned s1 = hi ? u[1] : u[3];
        unsigned s2 = hi ? u[4] : u[6];
        unsigned s3 = hi ? u[5] : u[7];
        unsigned r0 = __shfl_xor(s0, 32, 64);
        unsigned r1 = __shfl_xor(s1, 32, 64);
        unsigned r2 = __shfl_xor(s2, 32, 64);
        unsigned r3 = __shfl_xor(s3, 32, 64);

        union { unsigned w[4]; short8 v; } a0, a1;
        a0.w[0] = hi ? r0 : u[0];
        a0.w[1] = hi ? r1 : u[1];
        a0.w[2] = hi ? u[2] : r0;
        a0.w[3] = hi ? u[3] : r1;
        a1.w[0] = hi ? r2 : u[4];
        a1.w[1] = hi ? r3 : u[5];
        a1.w[2] = hi ? u[6] : r2;
        a1.w[3] = hi ? u[7] : r3;

        // O += P*V ; l += P*ones (row-sum on the MFMA pipe)
        o0 = __builtin_amdgcn_mfma_f32_32x32x16_bf16(a0.v, vf00, o0, 0, 0, 0);
        o0 = __builtin_amdgcn_mfma_f32_32x32x16_bf16(a1.v, vf10, o0, 0, 0, 0);
        o1 = __builtin_amdgcn_mfma_f32_32x32x16_bf16(a0.v, vf01, o1, 0, 0, 0);
        o1 = __builtin_amdgcn_mfma_f32_32x32x16_bf16(a1.v, vf11, o1, 0, 0, 0);
        ol = __builtin_amdgcn_mfma_f32_32x32x16_bf16(a0.v, ones.v, ol, 0, 0, 0);
        ol = __builtin_amdgcn_mfma_f32_32x32x16_bf16(a1.v, ones.v, ol, 0, 0, 0);
    };

    stage(0, 0);
    __syncthreads();

    for (int t = 0; t < NTILE; t += 2) {
        stage(t + 1, 1);
        tile_compute(&lds[0][0][0], &lds[0][1][0], t);
        __syncthreads();
        if (t + 2 < NTILE) stage(t + 2, 0);
        tile_compute(&lds[1][0][0], &lds[1][1][0], t + 1);
        __syncthreads();
    }

    // epilogue: unnormalized bf16 partials; ol[r] = l of row qrow(r)
#pragma unroll
    for (int r = 0; r < 16; ++r) {
        int qrow = (r & 3) + 8 * (r >> 2) + 4 * hi;
        size_t row = (size_t)z * NROWS + (size_t)bh * TT + q0 + qrow;
        unsigned short* Orow = Opart + row * 64;
        Orow[lq]      = f2bf(o0[r]);
        Orow[32 + lq] = f2bf(o1[r]);
    }
    if (lq == 0) {
#pragma unroll
        for (int r = 0; r < 16; ++r) {
            int qrow = (r & 3) + 8 * (r >> 2) + 4 * hi;
            lbuf[(size_t)z * NROWS + (size_t)bh * TT + q0 + qrow] = ol[r];
        }
    }
}

// ============================================================
// launch
// ============================================================
extern "C" void kernel_launch(void* const* d_in, const int* in_sizes, int n_in,
                              void* d_out, int out_size, void* d_ws, size_t ws_size,
                              hipStream_t stream) {
    const float* x      = (const float*)d_in[0];
    const float* W_qkv  = (const float*)d_in[1];
    const float* b_qkv  = (const float*)d_in[2];
    const float* W_out  = (const float*)d_in[3];
    const float* b_out  = (const float*)d_in[4];
    const unsigned char* mask = (const unsigned char*)d_in[5];
    float* out = (float*)d_out;

    char* ws = (char*)d_ws;
    size_t off = 0;
    auto alloc = [&](size_t bytes) { char* p = ws + off; off += (bytes + 255) & ~(size_t)255; return p; };

    unsigned short* Opart = (unsigned short*)alloc((size_t)SPLIT * NROWS * 64 * 2);  // 16.8 MB
    unsigned short* xb    = (unsigned short*)alloc((size_t)BT * DD * 2);
    unsigned short* wqkvt = (unsigned short*)alloc((size_t)N3 * DD * 2);
    unsigned short* woutt = (unsigned short*)alloc((size_t)DD * DD * 2);
    float2*         cs    = (float2*)        alloc((size_t)TT * 32 * 8);
    unsigned short* Qb    = (unsigned short*)alloc((size_t)BB * HH * TT * HDIM * 2);
    unsigned short* Kb    = (unsigned short*)alloc((size_t)BB * HH * TT * HDIM * 2);
    unsigned short* Vtb   = (unsigned short*)alloc((size_t)BB * HH * TT * HDIM * 2);
    float*          lbuf  = (float*)         alloc((size_t)SPLIT * NROWS * 4);
    unsigned*       mbits = (unsigned*)      alloc((size_t)BB * 64 * 4);

    // 1. fused prep
    k_prep<<<5377, 256, 0, stream>>>(x, W_qkv, W_out, mask, xb, cs, wqkvt, woutt, mbits);
    // 2. QKV GEMM with fused bias+RoPE+scatter, V written transposed (BK=64)
    k_gemm_qkv<<<768, 256, 0, stream>>>(xb, wqkvt, b_qkv, cs, Qb, Kb, Vtb);
    // 3. attention: 1024 blocks, 2-way KV split
    k_attn<<<dim3(16 * BB * HH * SPLIT), 256, 0, stream>>>(Qb, Kb, Vtb, mbits, Opart, lbuf);
    // 4. output GEMM with fused split-combine (64x128 tiles, 512 blocks)
    k_gemm_out<<<512, 256, 0, stream>>>(Opart, lbuf, woutt, b_out, out);
}

// Round 22
// 130.154 us; speedup vs baseline: 1.0463x; 1.0463x over previous
//
#include <hip/hip_runtime.h>
#include <hip/hip_bf16.h>
#include <math.h>

#define DEV_INLINE __device__ __forceinline__

typedef __attribute__((ext_vector_type(4))) float f32x4;
typedef __attribute__((ext_vector_type(16))) float f32x16;
typedef __attribute__((ext_vector_type(8))) short short8;
typedef __attribute__((ext_vector_type(4))) unsigned short u16x4;

// ---------- bf16 helpers ----------
DEV_INLINE unsigned short f2bf(float f) {
    unsigned int u = __builtin_bit_cast(unsigned int, f);
    u += 0x7FFFu + ((u >> 16) & 1u);   // round-to-nearest-even
    return (unsigned short)(u >> 16);
}
DEV_INLINE float bf2f(unsigned short h) {
    unsigned int u = ((unsigned int)h) << 16;
    return __builtin_bit_cast(float, u);
}
DEV_INLINE unsigned cvt_pk_bf16(float lo, float hi) {
    unsigned r;
    asm("v_cvt_pk_bf16_f32 %0, %1, %2" : "=v"(r) : "v"(lo), "v"(hi));
    return r;
}

// ---------- async global->LDS (16B per lane) ----------
DEV_INLINE void gload16(const void* g, void* l) {
    __builtin_amdgcn_global_load_lds(
        (const __attribute__((address_space(1))) unsigned int*)g,
        (__attribute__((address_space(3))) unsigned int*)l, 16, 0, 0);
}

// ---------- constants ----------
#define BB 2
#define TT 2048
#define DD 1024
#define HH 16
#define HDIM 64
#define BT (BB*TT)        // 4096
#define N3 (3*DD)         // 3072
#define NROWS (BB*HH*TT)  // 65536 attention rows
#define K1ATT 0.18033688011112042f   // (1/8) * log2(e), folded into Q

#define SPLIT 2
#define KVLEN (TT/SPLIT)   // 1024 keys per split
#define NTILE (KVLEN/32)   // 32 tiles per split

// ============================================================
// Fused prep kernel (block-range dispatch)
// ============================================================
DEV_INLINE void do_transpose(const float* __restrict__ in, unsigned short* __restrict__ out,
                             int K, int N, int bx, float (*tile)[66], int tid) {
    int nb = N >> 6;
    int n0 = (bx % nb) * 64, k0 = (bx / nb) * 64;
    int tx = tid & 63, ty = tid >> 6;
#pragma unroll
    for (int r = ty; r < 64; r += 4)
        tile[r][tx] = in[(size_t)(k0 + r) * N + n0 + tx];
    __syncthreads();
#pragma unroll
    for (int r = ty; r < 64; r += 4)
        out[(size_t)(n0 + r) * K + k0 + tx] = f2bf(tile[tx][r]);
}

__global__ __launch_bounds__(256)
void k_prep(const float* __restrict__ x, const float* __restrict__ W_qkv,
            const float* __restrict__ W_out, const unsigned char* __restrict__ mask,
            unsigned short* __restrict__ xb, float2* __restrict__ cs,
            unsigned short* __restrict__ wqkvt, unsigned short* __restrict__ woutt,
            unsigned* __restrict__ mbits) {
    __shared__ float tile[64][66];
    const int bid = blockIdx.x, tid = threadIdx.x;
    if (bid < 4096) {
        int i = bid * 256 + tid;
        f32x4 v = ((const f32x4*)x)[i];
        u16x4 o;
        o[0] = f2bf(v[0]); o[1] = f2bf(v[1]); o[2] = f2bf(v[2]); o[3] = f2bf(v[3]);
        ((u16x4*)xb)[i] = o;
    } else if (bid < 4352) {
        int i = (bid - 4096) * 256 + tid;
        int t = i >> 5, f = i & 31;
        float inv = powf(10000.0f, -(float)f / 32.0f);
        float ang = (float)t * inv;
        cs[i] = make_float2(cosf(ang), sinf(ang));
    } else if (bid < 5120) {
        do_transpose(W_qkv, wqkvt, DD, N3, bid - 4352, tile, tid);
    } else if (bid < 5376) {
        do_transpose(W_out, woutt, DD, DD, bid - 5120, tile, tid);
    } else {
        if (tid < BB * 64) {
            int b = tid >> 6, w = tid & 63;
            unsigned v = 0;
#pragma unroll
            for (int j = 0; j < 32; ++j)
                v |= (mask[b * TT + w * 32 + j] ? 1u : 0u) << j;
            mbits[tid] = v;
        }
    }
}

// ============================================================
// Shared BK=64 GEMM core (R17-proven): 128x128 tile, 16 K-steps.
// XOR-swizzled LDS (both-sides rule).
// ============================================================
#define GEMM64_BODY(A_, Bt_, m0_, n0_, K_)                                          \
    f32x4 acc[4][4] = {};                                                           \
    for (int k0 = 0; k0 < (K_); k0 += 64) {                                         \
        __syncthreads();                                                            \
        _Pragma("unroll")                                                           \
        for (int i = 0; i < 4; ++i) {                                               \
            int c    = i * 256 + tid;                                               \
            int row  = c >> 3;                                                      \
            int dstc = c & 7;                                                       \
            int srcc = dstc ^ (row & 7);                                            \
            unsigned short* ldsA = As + (size_t)(i * 256 + wave * 64) * 8;          \
            unsigned short* ldsB = Bs + (size_t)(i * 256 + wave * 64) * 8;          \
            gload16(A_  + (size_t)((m0_) + row) * (K_) + k0 + srcc * 8, ldsA);      \
            gload16(Bt_ + (size_t)((n0_) + row) * (K_) + k0 + srcc * 8, ldsB);      \
        }                                                                           \
        __syncthreads();                                                            \
        _Pragma("unroll")                                                           \
        for (int kk = 0; kk < 2; ++kk) {                                            \
            short8 af[4], bfr[4];                                                   \
            _Pragma("unroll")                                                       \
            for (int m = 0; m < 4; ++m) {                                           \
                int R  = wr * 64 + m * 16 + lrow;                                   \
                int ch = (kk * 4 + (lane >> 4)) ^ (R & 7);                          \
                af[m] = *(const short8*)(As + R * 64 + ch * 8);                     \
            }                                                                       \
            _Pragma("unroll")                                                       \
            for (int n = 0; n < 4; ++n) {                                           \
                int R  = wc * 64 + n * 16 + lrow;                                   \
                int ch = (kk * 4 + (lane >> 4)) ^ (R & 7);                          \
                bfr[n] = *(const short8*)(Bs + R * 64 + ch * 8);                    \
            }                                                                       \
            _Pragma("unroll")                                                       \
            for (int m = 0; m < 4; ++m)                                             \
                _Pragma("unroll")                                                   \
                for (int n = 0; n < 4; ++n)                                         \
                    acc[m][n] = __builtin_amdgcn_mfma_f32_16x16x32_bf16(            \
                        af[m], bfr[n], acc[m][n], 0, 0, 0);                         \
        }                                                                           \
    }

// ============================================================
// QKV GEMM + fused bias + RoPE + scatter. BK=64 core.
// V written transposed directly (R19-proven).
// ============================================================
__global__ __launch_bounds__(256)
void k_gemm_qkv(const unsigned short* __restrict__ A,
                const unsigned short* __restrict__ Bt,
                const float* __restrict__ bias,
                const float2* __restrict__ cs,
                unsigned short* __restrict__ Qb,
                unsigned short* __restrict__ Kb,
                unsigned short* __restrict__ Vt) {
    __shared__ unsigned short As[128 * 64];
    __shared__ unsigned short Bs[128 * 64];
    const int tid  = threadIdx.x;
    const int lane = tid & 63;
    const int wave = tid >> 6;
    const int wr = wave >> 1, wc = wave & 1;
    const int bid = blockIdx.x;
    const int xcd = bid & 7, loc = bid >> 3;                 // loc 0..95
    const int m0 = ((xcd >> 1) * 8 + (loc & 7)) * 128;       // 32 m-tiles
    const int n0 = ((xcd & 1) * 12 + (loc >> 3)) * 128;      // 24 n-tiles
    const int lrow = lane & 15;

    GEMM64_BODY(A, Bt, m0, n0, DD)

    const int part = n0 >> 10;                       // 0=Q 1=K 2=V
    const int n0c  = n0 + wc * 64;
    const int h    = ((n0 & 1023) + wc * 64) >> 6;

    if (part < 2) {
        unsigned short* Dst = part == 0 ? Qb : Kb;
        const float qs = part == 0 ? K1ATT : 1.0f;
#pragma unroll
        for (int m = 0; m < 4; ++m)
#pragma unroll
            for (int r = 0; r < 4; ++r) {
                int gm = m0 + wr * 64 + m * 16 + (lane >> 4) * 4 + r;
                int b = gm >> 11, t = gm & (TT - 1);
                size_t rowoff = ((size_t)(b * HH + h) * TT + t) * 64;
#pragma unroll
                for (int n = 0; n < 2; ++n) {
                    int dr = n * 16 + lrow;
                    float2 c2 = cs[t * 32 + dr];
                    float lo = acc[m][n][r]     + bias[n0c + dr];
                    float hi = acc[m][n + 2][r] + bias[n0c + 32 + dr];
                    Dst[rowoff + dr]      = f2bf((lo * c2.x - hi * c2.y) * qs);
                    Dst[rowoff + 32 + dr] = f2bf((hi * c2.x + lo * c2.y) * qs);
                }
            }
    } else {
        // V: direct transposed write
#pragma unroll
        for (int m = 0; m < 4; ++m) {
            int gm0 = m0 + wr * 64 + m * 16 + (lane >> 4) * 4;  // 4 consecutive t
            int b = gm0 >> 11, t = gm0 & (TT - 1);
#pragma unroll
            for (int n = 0; n < 4; ++n) {
                int d = n * 16 + lrow;
                float bv = bias[n0c + d];
                u16x4 v;
#pragma unroll
                for (int r = 0; r < 4; ++r) v[r] = f2bf(acc[m][n][r] + bv);
                *(u16x4*)(Vt + ((size_t)(b * HH + h) * 64 + d) * TT + t) = v;
            }
        }
    }
}

// ============================================================
// Output GEMM with FUSED split-combine (R20-proven).
// Tile 64x128, grid 512 (2 blocks/CU); 4 waves as 1x4.
// ============================================================
__global__ __launch_bounds__(256)
void k_gemm_out(const unsigned short* __restrict__ Opart,
                const float* __restrict__ lbuf,
                const unsigned short* __restrict__ Bt,
                const float* __restrict__ bias,
                float* __restrict__ C) {
    __shared__ unsigned short As[64 * 64];     // 8 KB
    __shared__ unsigned short Bs[128 * 64];    // 16 KB
    const int tid  = threadIdx.x;
    const int lane = tid & 63;
    const int wave = tid >> 6;
    const int bid = blockIdx.x;
    const int xcd = bid & 7, loc = bid >> 3;                 // loc 0..63
    const int m0 = ((xcd >> 1) * 16 + (loc & 15)) * 64;      // 64 m-tiles
    const int n0 = ((xcd & 1) * 4 + (loc >> 4)) * 128;       // 8 n-tiles
    const int lrow = lane & 15;
    const int N = DD, K = DD;

    f32x4 acc[4][2] = {};

    for (int k0 = 0; k0 < K; k0 += 64) {
        const int h = k0 >> 6;                 // head for this K-step
        __syncthreads();
        // ---- A: reg-staged combine (2 slots/thread) ----
#pragma unroll
        for (int i = 0; i < 2; ++i) {
            int c     = i * 256 + tid;
            int row   = c >> 3;                // 0..63 (tile row)
            int chunk = c & 7;                 // d-chunk
            int gm = m0 + row;
            int b  = gm >> 11, t = gm & (TT - 1);
            size_t g = (size_t)(b * HH + h) * TT + t;
            short8 va = *(const short8*)(Opart + g * 64 + chunk * 8);
            short8 vb = *(const short8*)(Opart + ((size_t)NROWS + g) * 64 + chunk * 8);
            float inv = 1.0f / (lbuf[g] + lbuf[NROWS + g]);
            short8 o;
#pragma unroll
            for (int e = 0; e < 8; ++e)
                o[e] = (short)f2bf((bf2f((unsigned short)va[e]) + bf2f((unsigned short)vb[e])) * inv);
            *(short8*)(As + row * 64 + (chunk ^ (row & 7)) * 8) = o;
        }
        // ---- B: gload16 (4 slots/thread), inverse-swizzled source ----
#pragma unroll
        for (int i = 0; i < 4; ++i) {
            int c    = i * 256 + tid;
            int row  = c >> 3;
            int dstc = c & 7;
            int srcc = dstc ^ (row & 7);
            gload16(Bt + (size_t)(n0 + row) * K + k0 + srcc * 8,
                    &Bs[(size_t)(i * 256 + wave * 64) * 8]);
        }
        __syncthreads();
        // ---- compute: wave covers m 0..63, n wave*32..+32 ----
#pragma unroll
        for (int kk = 0; kk < 2; ++kk) {
            short8 af[4], bfr[2];
#pragma unroll
            for (int m = 0; m < 4; ++m) {
                int R  = m * 16 + lrow;
                int ch = (kk * 4 + (lane >> 4)) ^ (R & 7);
                af[m] = *(const short8*)(As + R * 64 + ch * 8);
            }
#pragma unroll
            for (int n = 0; n < 2; ++n) {
                int R  = wave * 32 + n * 16 + lrow;
                int ch = (kk * 4 + (lane >> 4)) ^ (R & 7);
                bfr[n] = *(const short8*)(Bs + R * 64 + ch * 8);
            }
#pragma unroll
            for (int m = 0; m < 4; ++m)
#pragma unroll
                for (int n = 0; n < 2; ++n)
                    acc[m][n] = __builtin_amdgcn_mfma_f32_16x16x32_bf16(
                        af[m], bfr[n], acc[m][n], 0, 0, 0);
        }
    }

#pragma unroll
    for (int m = 0; m < 4; ++m) {
        int row = m0 + m * 16 + (lane >> 4) * 4;
#pragma unroll
        for (int n = 0; n < 2; ++n) {
            int col = n0 + wave * 32 + n * 16 + lrow;
            float bv = bias[col];
#pragma unroll
            for (int r = 0; r < 4; ++r)
                C[(size_t)(row + r) * N + col] = acc[m][n][r] + bv;
        }
    }
}

// ============================================================
// Flash attention (R13/R20-proven): swapped-QK^T 32x32,
// KVBLK=32, LDS dbuf, fixed-max softmax, SPLIT=2, XCD swizzle,
// bf16 partials. (R21's ones-MFMA l-sum REGRESSED: +25% MFMA
// issue > VALU savings; VALU l-tree restored.)
// ============================================================
__global__ __launch_bounds__(256, 4)
void k_attn(const unsigned short* __restrict__ Q,
            const unsigned short* __restrict__ Kg,
            const unsigned short* __restrict__ Vt,
            const unsigned* __restrict__ mbits,
            unsigned short* __restrict__ Opart, float* __restrict__ lbuf) {
    __shared__ unsigned short lds[2][2][2048];   // [buf][K/V][32x64]
    const int tid = threadIdx.x, lane = tid & 63, wave = tid >> 6;
    const int bid = blockIdx.x;
    const int w   = (bid & 7) * 128 + (bid >> 3);
    const int qx  = w & 15;
    const int z   = (w >> 4) & 1;
    const int bh  = w >> 5;
    const int b   = bh >> 4;
    const int q0  = (qx * 4 + wave) * 32;
    const int lq  = lane & 31;
    const int hi  = lane >> 5;
    const int k0  = z * KVLEN;

    const unsigned short* Qp = Q  + ((size_t)bh * TT + q0) * 64;
    const unsigned short* Kp = Kg + (size_t)bh * TT * 64 + (size_t)k0 * 64;
    const unsigned short* Vp = Vt + (size_t)bh * 64 * TT + k0;

    unsigned mwv = mbits[b * 64 + z * 32 + lq];

    const int rr = wave * 8 + (lane >> 3);
    const int j  = (lane & 7) ^ (rr & 7);
    const size_t ksrc = (size_t)rr * 64 + j * 8;
    const int vd = rr + ((j >> 2) << 5);
    const size_t vsrc = (size_t)vd * TT + (j & 3) * 8;

    short8 qf[4];
#pragma unroll
    for (int c = 0; c < 4; ++c)
        qf[c] = *(const short8*)(Qp + lq * 64 + c * 16 + hi * 8);

    f32x16 o0 = {}, o1 = {};
    float lhalf = 0.f;
    const int rx = lq & 7;

    auto stage = [&](int tt, int buf) {
        gload16(Kp + (size_t)tt * 32 * 64 + ksrc, &lds[buf][0][wave * 512]);
        gload16(Vp + tt * 32 + vsrc,              &lds[buf][1][wave * 512]);
    };

    auto tile_compute = [&](const unsigned short* Kl, const unsigned short* Vl, int t) {
        short8 kf0 = *(const short8*)(Kl + lq * 64 + ((0 + hi) ^ rx) * 8);
        short8 kf1 = *(const short8*)(Kl + lq * 64 + ((2 + hi) ^ rx) * 8);
        short8 kf2 = *(const short8*)(Kl + lq * 64 + ((4 + hi) ^ rx) * 8);
        short8 kf3 = *(const short8*)(Kl + lq * 64 + ((6 + hi) ^ rx) * 8);
        short8 vf00 = *(const short8*)(Vl + lq * 64 + ((0 + hi) ^ rx) * 8);
        short8 vf10 = *(const short8*)(Vl + lq * 64 + ((2 + hi) ^ rx) * 8);
        short8 vf01 = *(const short8*)(Vl + lq * 64 + ((4 + hi) ^ rx) * 8);
        short8 vf11 = *(const short8*)(Vl + lq * 64 + ((6 + hi) ^ rx) * 8);

        f32x16 s = {};
        __builtin_amdgcn_s_setprio(1);
        s = __builtin_amdgcn_mfma_f32_32x32x16_bf16(kf0, qf[0], s, 0, 0, 0);
        s = __builtin_amdgcn_mfma_f32_32x32x16_bf16(kf1, qf[1], s, 0, 0, 0);
        s = __builtin_amdgcn_mfma_f32_32x32x16_bf16(kf2, qf[2], s, 0, 0, 0);
        s = __builtin_amdgcn_mfma_f32_32x32x16_bf16(kf3, qf[3], s, 0, 0, 0);
        __builtin_amdgcn_s_setprio(0);

        unsigned mw = __builtin_amdgcn_readlane(mwv, t);
        float p[16];
        if (mw) {
            unsigned bmh = mw >> (hi * 4);
#pragma unroll
            for (int r = 0; r < 16; ++r) {
                float v = s[r];
                if ((bmh >> ((r & 3) + 8 * (r >> 2))) & 1u) v = -INFINITY;
                p[r] = __builtin_amdgcn_exp2f(v);
            }
        } else {
#pragma unroll
            for (int r = 0; r < 16; ++r) p[r] = __builtin_amdgcn_exp2f(s[r]);
        }

        float ts[8];
#pragma unroll
        for (int r = 0; r < 8; ++r) ts[r] = p[r] + p[r + 8];
#pragma unroll
        for (int r = 0; r < 4; ++r) ts[r] = ts[r] + ts[r + 4];
        lhalf += (ts[0] + ts[1]) + (ts[2] + ts[3]);

        unsigned u[8];
#pragma unroll
        for (int i = 0; i < 8; ++i) u[i] = cvt_pk_bf16(p[2 * i], p[2 * i + 1]);

        unsigned s0 = hi ? u[0] : u[2];
        unsigned s1 = hi ? u[1] : u[3];
        unsigned s2 = hi ? u[4] : u[6];
        unsigned s3 = hi ? u[5] : u[7];
        unsigned r0 = __shfl_xor(s0, 32, 64);
        unsigned r1 = __shfl_xor(s1, 32, 64);
        unsigned r2 = __shfl_xor(s2, 32, 64);
        unsigned r3 = __shfl_xor(s3, 32, 64);

        union { unsigned w[4]; short8 v; } a0, a1;
        a0.w[0] = hi ? r0 : u[0];
        a0.w[1] = hi ? r1 : u[1];
        a0.w[2] = hi ? u[2] : r0;
        a0.w[3] = hi ? u[3] : r1;
        a1.w[0] = hi ? r2 : u[4];
        a1.w[1] = hi ? r3 : u[5];
        a1.w[2] = hi ? u[6] : r2;
        a1.w[3] = hi ? u[7] : r3;

        __builtin_amdgcn_s_setprio(1);
        o0 = __builtin_amdgcn_mfma_f32_32x32x16_bf16(a0.v, vf00, o0, 0, 0, 0);
        o0 = __builtin_amdgcn_mfma_f32_32x32x16_bf16(a1.v, vf10, o0, 0, 0, 0);
        o1 = __builtin_amdgcn_mfma_f32_32x32x16_bf16(a0.v, vf01, o1, 0, 0, 0);
        o1 = __builtin_amdgcn_mfma_f32_32x32x16_bf16(a1.v, vf11, o1, 0, 0, 0);
        __builtin_amdgcn_s_setprio(0);
    };

    stage(0, 0);
    __syncthreads();

    for (int t = 0; t < NTILE; t += 2) {
        stage(t + 1, 1);
        tile_compute(&lds[0][0][0], &lds[0][1][0], t);
        __syncthreads();
        if (t + 2 < NTILE) stage(t + 2, 0);
        tile_compute(&lds[1][0][0], &lds[1][1][0], t + 1);
        __syncthreads();
    }

    // epilogue: unnormalized bf16 partials + f32 l
    float ltot = lhalf + __shfl_xor(lhalf, 32, 64);
#pragma unroll
    for (int r = 0; r < 16; ++r) {
        int qrow = (r & 3) + 8 * (r >> 2) + 4 * hi;
        size_t row = (size_t)z * NROWS + (size_t)bh * TT + q0 + qrow;
        unsigned short* Orow = Opart + row * 64;
        Orow[lq]      = f2bf(o0[r]);
        Orow[32 + lq] = f2bf(o1[r]);
    }
    if (hi == 0)
        lbuf[(size_t)z * NROWS + (size_t)bh * TT + q0 + lq] = ltot;
}

// ============================================================
// launch
// ============================================================
extern "C" void kernel_launch(void* const* d_in, const int* in_sizes, int n_in,
                              void* d_out, int out_size, void* d_ws, size_t ws_size,
                              hipStream_t stream) {
    const float* x      = (const float*)d_in[0];
    const float* W_qkv  = (const float*)d_in[1];
    const float* b_qkv  = (const float*)d_in[2];
    const float* W_out  = (const float*)d_in[3];
    const float* b_out  = (const float*)d_in[4];
    const unsigned char* mask = (const unsigned char*)d_in[5];
    float* out = (float*)d_out;

    char* ws = (char*)d_ws;
    size_t off = 0;
    auto alloc = [&](size_t bytes) { char* p = ws + off; off += (bytes + 255) & ~(size_t)255; return p; };

    unsigned short* Opart = (unsigned short*)alloc((size_t)SPLIT * NROWS * 64 * 2);  // 16.8 MB
    unsigned short* xb    = (unsigned short*)alloc((size_t)BT * DD * 2);
    unsigned short* wqkvt = (unsigned short*)alloc((size_t)N3 * DD * 2);
    unsigned short* woutt = (unsigned short*)alloc((size_t)DD * DD * 2);
    float2*         cs    = (float2*)        alloc((size_t)TT * 32 * 8);
    unsigned short* Qb    = (unsigned short*)alloc((size_t)BB * HH * TT * HDIM * 2);
    unsigned short* Kb    = (unsigned short*)alloc((size_t)BB * HH * TT * HDIM * 2);
    unsigned short* Vtb   = (unsigned short*)alloc((size_t)BB * HH * TT * HDIM * 2);
    float*          lbuf  = (float*)         alloc((size_t)SPLIT * NROWS * 4);
    unsigned*       mbits = (unsigned*)      alloc((size_t)BB * 64 * 4);

    // 1. fused prep
    k_prep<<<5377, 256, 0, stream>>>(x, W_qkv, W_out, mask, xb, cs, wqkvt, woutt, mbits);
    // 2. QKV GEMM with fused bias+RoPE+scatter, V written transposed (BK=64)
    k_gemm_qkv<<<768, 256, 0, stream>>>(xb, wqkvt, b_qkv, cs, Qb, Kb, Vtb);
    // 3. attention: 1024 blocks, 2-way KV split
    k_attn<<<dim3(16 * BB * HH * SPLIT), 256, 0, stream>>>(Qb, Kb, Vtb, mbits, Opart, lbuf);
    // 4. output GEMM with fused split-combine (64x128 tiles, 512 blocks)
    k_gemm_out<<<512, 256, 0, stream>>>(Opart, lbuf, woutt, b_out, out);
}